// Round 3
// baseline (153.768 us; speedup 1.0000x reference)
//
#include <hip/hip_runtime.h>
#include <hip/hip_bf16.h>
#include <math.h>

// Problem constants
#define SEQ 4096
#define DM  1024
#define NIMU 72
#define NNOISE 12
#define NJ (NIMU*NNOISE)     // 864
#define TSTEPS 300
#define PLANE (NIMU*SEQ)     // 294912

// Fragment-linear layouts (16x16x32 bf16 MFMA operand granules):
//   granule(tile, ch) = 512 shorts; lane l holds 8 shorts at +l*8:
//     row = l&15 (m or n), k = ch*32 + (l>>4)*8 + 0..7
//   ch 0..31 = hi half (k 0..1023), ch 32..63 = lo half.
// A2f : 256 s_tiles x 64 ch x 512 shorts = 16.78 MB
// Btf : 56  j_tiles x 64 ch x 512 shorts =  3.67 MB (j_tiles 54,55 unwritten junk)
// pt  : 864 x 4096 f32 (planes >= 576 never written/read after R11 epilogue fold)
#define A2F_SHORTS ((size_t)256 * 64 * 512)
#define BTF_SHORTS ((size_t)56 * 64 * 512)

typedef __attribute__((ext_vector_type(8))) short bf16x8;
typedef __attribute__((ext_vector_type(4))) float f32x4;
typedef __attribute__((ext_vector_type(2))) float f32x2;

__device__ __forceinline__ float softplus_f(float x) {
    return fmaxf(x, 0.f) + log1pf(expf(-fabsf(x)));
}

// round-to-nearest-even bf16 split: x ~= hi + lo with |err| ~ 2^-16 * |x|
__device__ __forceinline__ void split_bf16(float x, short& hi, short& lo) {
    unsigned b = __float_as_uint(x);
    unsigned h = (b + 0x7FFFu + ((b >> 16) & 1u)) >> 16;
    float hf = __uint_as_float(h << 16);
    float r = x - hf;
    unsigned b2 = __float_as_uint(r);
    unsigned l2 = (b2 + 0x7FFFu + ((b2 >> 16) & 1u)) >> 16;
    hi = (short)h;
    lo = (short)l2;
}

// ---------------- 1. LayerNorm -> A2f (fragment-linear bf16 hi|lo) ----------------
__global__ __launch_bounds__(256) void ln_kernel(const float* __restrict__ x,
                                                 const float* __restrict__ gamma,
                                                 const float* __restrict__ beta,
                                                 short* __restrict__ A2f) {
    const int s_tile = blockIdx.x;
    const int tid = threadIdx.x;
    const int mrow = tid >> 4;      // row within s_tile
    const int g    = tid & 15;
    const int row  = s_tile * 16 + mrow;
    const float4* xr = (const float4*)(x + (size_t)row * DM);

    float s = 0.f, sq = 0.f;
    #pragma unroll
    for (int i = 0; i < 16; ++i) {
        float4 v = xr[g + 16 * i];
        s  += v.x + v.y + v.z + v.w;
        sq += v.x*v.x + v.y*v.y + v.z*v.z + v.w*v.w;
    }
    #pragma unroll
    for (int off = 1; off < 16; off <<= 1) {
        s  += __shfl_xor(s, off);
        sq += __shfl_xor(sq, off);
    }
    const float mean = s * (1.f / DM);
    const float var  = sq * (1.f / DM) - mean * mean;
    const float rstd = rsqrtf(fmaxf(var, 0.f) + 1e-5f);

    #pragma unroll
    for (int i = 0; i < 16; ++i) {
        float4 v = xr[g + 16 * i];
        float4 gm = ((const float4*)gamma)[g + 16 * i];
        float4 bt = ((const float4*)beta)[g + 16 * i];
        float o[4];
        o[0] = (v.x - mean) * rstd * gm.x + bt.x;
        o[1] = (v.y - mean) * rstd * gm.y + bt.y;
        o[2] = (v.z - mean) * rstd * gm.z + bt.z;
        o[3] = (v.w - mean) * rstd * gm.w + bt.w;
        short4 hv, lv;
        split_bf16(o[0], hv.x, lv.x);
        split_bf16(o[1], hv.y, lv.y);
        split_bf16(o[2], hv.z, lv.z);
        split_bf16(o[3], hv.w, lv.w);
        const int ch = (g >> 3) + 2 * i;
        const size_t base = ((size_t)s_tile * 64 + ch) * 512
                          + mrow * 8 + ((g >> 1) & 3) * 128 + (g & 1) * 4;
        *(short4*)(A2f + base)             = hv;   // hi: ch
        *(short4*)(A2f + base + 32 * 512)  = lv;   // lo: ch+32
    }
}

// ---------------- 2a. W -> Btf (transpose + split, fragment-linear) ----------------
__global__ __launch_bounds__(256) void wprep_kernel(const float* __restrict__ W,
                                                    short* __restrict__ Btf) {
    __shared__ float T[32][33];
    const int k0 = blockIdx.x * 32, j0 = blockIdx.y * 32;
    const int t = threadIdx.x;
    {
        const int r = t >> 3, c4 = (t & 7) * 4;
        float4 v = *(const float4*)(W + (size_t)(k0 + r) * NJ + j0 + c4);
        T[r][c4 + 0] = v.x; T[r][c4 + 1] = v.y; T[r][c4 + 2] = v.z; T[r][c4 + 3] = v.w;
    }
    __syncthreads();
    if (t < 128) {
        const int gq = t >> 6;          // which 16-j group
        const int l  = t & 63;
        const int n = l & 15, c = l >> 4;
        const int jt = blockIdx.y * 2 + gq;       // j_tile
        bf16x8 hv, lv;
        #pragma unroll
        for (int o = 0; o < 8; ++o) {
            short h, lo_;
            split_bf16(T[c * 8 + o][gq * 16 + n], h, lo_);
            hv[o] = h; lv[o] = lo_;
        }
        short* dh = Btf + ((size_t)jt * 64 + blockIdx.x) * 512 + l * 8;
        *(bf16x8*)dh = hv;
        *(bf16x8*)(dh + (size_t)32 * 512) = lv;   // lo chunk = ch+32
    }
}

// ---------------- 2b. Barrier-free MFMA GEMM + fused tail epilogue ----------------
// R11: (a) 1D grid + XCD-grouping swizzle: xcd c = bid&7 owns bx in [4c,4c+4) x all
// 7 by -> the 7 blocks sharing an A2f row-panel (4.2 MB) are co-XCD, panel fetched
// once into that XCD's L2 instead of 7x via L3 (~117 MB -> ~17 MB panel traffic).
// (b) j >= 576 (noise planes 8..11, tile-aligned: jt >= 36) write directly to out
// (softplus on odd noise) -- tail_kernel deleted, pt planes 8..11 never touched.
__global__ __launch_bounds__(256, 1) void gemm_kernel(const short* __restrict__ A2f,
                                                      const short* __restrict__ Btf,
                                                      const float* __restrict__ bias,
                                                      float* __restrict__ pt,
                                                      float* __restrict__ out) {
    const int bid = blockIdx.x;
    const int c = bid & 7, k = bid >> 3;
    const int kd7 = k / 7;
    const int bx = c * 4 + kd7;
    const int by = k - kd7 * 7;
    const int l = threadIdx.x & 63, w = threadIdx.x >> 6;
    const int st0 = bx * 8 + (w & 1) * 4;    // wave's m-tile base
    const int jt0 = by * 8 + (w >> 1) * 4;   // wave's n-tile base
    const short* aB = A2f + (size_t)st0 * (64 * 512) + l * 8;
    const short* bB = Btf + (size_t)jt0 * (64 * 512) + l * 8;

    f32x4 acc[4][4] = {};
    bf16x8 ah[2][4], al[2][4], bh[2][4], bl[2][4];

    auto ldstep = [&](int slot, int i) {
        #pragma unroll
        for (int t = 0; t < 4; ++t) {
            ah[slot][t] = *(const bf16x8*)(aB + ((size_t)t * 64 + i) * 512);
            al[slot][t] = *(const bf16x8*)(aB + ((size_t)t * 64 + 32 + i) * 512);
            bh[slot][t] = *(const bf16x8*)(bB + ((size_t)t * 64 + i) * 512);
            bl[slot][t] = *(const bf16x8*)(bB + ((size_t)t * 64 + 32 + i) * 512);
        }
    };

    ldstep(0, 0);
    #pragma unroll 2
    for (int i = 0; i < 32; ++i) {
        const int cur = i & 1;
        if (i + 1 < 32) ldstep(cur ^ 1, i + 1);   // loads in flight during MFMA
        #pragma unroll
        for (int mi = 0; mi < 4; ++mi)
            #pragma unroll
            for (int ni = 0; ni < 4; ++ni)
                acc[mi][ni] = __builtin_amdgcn_mfma_f32_16x16x32_bf16(
                    ah[cur][mi], bh[cur][ni], acc[mi][ni], 0, 0, 0);
        #pragma unroll
        for (int mi = 0; mi < 4; ++mi)
            #pragma unroll
            for (int ni = 0; ni < 4; ++ni)
                acc[mi][ni] = __builtin_amdgcn_mfma_f32_16x16x32_bf16(
                    ah[cur][mi], bl[cur][ni], acc[mi][ni], 0, 0, 0);
        #pragma unroll
        for (int mi = 0; mi < 4; ++mi)
            #pragma unroll
            for (int ni = 0; ni < 4; ++ni)
                acc[mi][ni] = __builtin_amdgcn_mfma_f32_16x16x32_bf16(
                    al[cur][mi], bh[cur][ni], acc[mi][ni], 0, 0, 0);
    }

    // epilogue: C/D layout col=lane&15 (j-within-tile), row=(lane>>4)*4+reg (s)
    const int srow = (l >> 4) * 4;
    const int jcol = l & 15;
    #pragma unroll
    for (int ni = 0; ni < 4; ++ni) {
        const int jt = jt0 + ni;
        const int j = jt * 16 + jcol;
        if (j < NJ) {
            const float bj = bias[j];
            if (jt < 36) {                       // noise planes 0..7 -> pt (spring input)
                #pragma unroll
                for (int mi = 0; mi < 4; ++mi) {
                    f32x4 v = acc[mi][ni];
                    v[0] += bj; v[1] += bj; v[2] += bj; v[3] += bj;
                    *(f32x4*)(pt + (size_t)j * SEQ + (st0 + mi) * 16 + srow) = v;
                }
            } else {                             // noise planes 8..11 -> out directly
                const int noise = j / 72;        // 8..11
                const int imu = j - noise * 72;
                float* dst = out + (size_t)(noise - 7) * PLANE + (size_t)imu * SEQ;
                const bool sp = (noise & 1);
                #pragma unroll
                for (int mi = 0; mi < 4; ++mi) {
                    f32x4 v = acc[mi][ni];
                    v[0] += bj; v[1] += bj; v[2] += bj; v[3] += bj;
                    if (sp) {
                        v[0] = softplus_f(v[0]); v[1] = softplus_f(v[1]);
                        v[2] = softplus_f(v[2]); v[3] = softplus_f(v[3]);
                    }
                    *(f32x4*)(dst + (st0 + mi) * 16 + srow) = v;
                }
            }
        }
    }
}

// ---------------- 3. Spring recurrence + wave-private LDS-window scatter ----------------
// R10 (146us total): wave-private window, RMW chain ds_read2 -> wait -> add ->
// ds_write2 -> barrier = ONE full LDS-latency stall per macro-step (150 waits).
// R11: 3-parity buffers w3[j%3]. A barrier-group = 3 macro-steps; each buffer is
// RMW'd at exactly one step index per group (plus the B-stream +150 slot: lane
// distance 150 > 63 -> race-free), so all 6 reads issue together -> ONE lgkm wait
// per 3 macro-steps (50 waits). Cross-group RAW (lane l reads what lane l+3 wrote
// last group) pinned by one memory-clobber per group + in-order LDS pipe.
// Issue floor: 50 x (6 DS + ~40 VALU) x 4.5 waves/SIMD ~ 26K cyc ~ 11us.
__global__ __launch_bounds__(256) void spring_kernel(const float* __restrict__ pt,
                                                     float* __restrict__ kin) {
    __shared__ float w3[3][4 * 368];           // 363 used per wave per parity
    const int tid  = threadIdx.x;
    const int lane = tid & 63;
    const int wid  = tid >> 6;
    const int s0   = blockIdx.x * 256;
    const int imu  = blockIdx.y;
    const int s    = s0 + (wid << 6) + lane;

    // zero own windows (wave-private: no barrier needed before main loop)
    #pragma unroll
    for (int b = 0; b < 3; ++b)
        #pragma unroll
        for (int i = 0; i < 6; ++i) {
            const int idx = lane + i * 64;
            if (idx < 363) w3[b][wid * 368 + idx] = 0.f;
        }

    const int base = imu * SEQ + s;
    const float p0  = pt[(size_t)0 * PLANE + base];
    const float p1  = pt[(size_t)1 * PLANE + base];
    const float p2  = pt[(size_t)2 * PLANE + base];
    const float p3  = pt[(size_t)3 * PLANE + base];
    const float c1  = pt[(size_t)4 * PLANE + base];
    const float c2  = pt[(size_t)5 * PLANE + base];
    const float ph1 = pt[(size_t)6 * PLANE + base];
    const float ph2 = pt[(size_t)7 * PLANE + base];

    float dd = softplus_f(p1);
    float kk = dd * dd * 0.25f + softplus_f(p0);
    float om1 = 0.5f * sqrtf(fmaxf(4.f * kk - dd * dd, 0.f));
    float dt = softplus_f(p3);
    float kt = dt * dt * 0.25f + softplus_f(p2);
    float om2 = 0.5f * sqrtf(fmaxf(4.f * kt - dt * dt, 0.f));
    float e1 = expf(-0.5f * dd), e2 = expf(-0.5f * dt);
    float sn, cs, sn2, cs2;
    sincosf(om1, &sn, &cs);
    sincosf(om2, &sn2, &cs2);
    f32x2 Rr = {e1 * cs, e2 * cs2};          // per-step rotation (packed: osc1, osc2)
    f32x2 Ri = {e1 * sn, e2 * sn2};
    sincosf(ph1, &sn, &cs);
    sincosf(ph2, &sn2, &cs2);
    f32x2 zr = {c1 * cs, c2 * cs2};          // stream A state (t = 0)
    f32x2 zi = {c1 * sn, c2 * sn2};

    // stream B state: z * R^150 (exp-by-squaring)
    f32x2 zrB, ziB;
    {
        f32x2 prr = Rr, pri = Ri;
        f32x2 qr = {1.f, 1.f}, qi = {0.f, 0.f};
        int e = 150;
        while (e) {
            if (e & 1) {
                f32x2 nr = qr * prr - qi * pri;
                qi = qr * pri + qi * prr;
                qr = nr;
            }
            f32x2 nr = prr * prr - pri * pri;
            pri = 2.f * prr * pri;
            prr = nr;
            e >>= 1;
        }
        f32x2 nr = zr * qr - zi * qi;
        ziB = zr * qi + zi * qr;
        zrB = nr;
    }

    float* q0 = &w3[0][wid * 368 + lane];
    float* q1 = &w3[1][wid * 368 + lane];
    float* q2 = &w3[2][wid * 368 + lane];

    #pragma unroll 1
    for (int j = 0; j < 150; j += 3) {
        // values for macro-steps j, j+1, j+2 on both streams
        float vA0 = zi.x + zi.y;
        { f32x2 nr = zr * Rr - zi * Ri; zi = zr * Ri + zi * Rr; zr = nr; }
        float vA1 = zi.x + zi.y;
        { f32x2 nr = zr * Rr - zi * Ri; zi = zr * Ri + zi * Rr; zr = nr; }
        float vA2 = zi.x + zi.y;
        { f32x2 nr = zr * Rr - zi * Ri; zi = zr * Ri + zi * Rr; zr = nr; }
        float vB0 = ziB.x + ziB.y;
        { f32x2 nr = zrB * Rr - ziB * Ri; ziB = zrB * Ri + ziB * Rr; zrB = nr; }
        float vB1 = ziB.x + ziB.y;
        { f32x2 nr = zrB * Rr - ziB * Ri; ziB = zrB * Ri + ziB * Rr; zrB = nr; }
        float vB2 = ziB.x + ziB.y;
        { f32x2 nr = zrB * Rr - ziB * Ri; ziB = zrB * Ri + ziB * Rr; zrB = nr; }

        // all 6 reads issue together -> single lgkm wait per group
        const float a0 = q0[j],     b0 = q0[j + 150];
        const float a1 = q1[j + 1], b1 = q1[j + 151];
        const float a2 = q2[j + 2], b2 = q2[j + 152];
        q0[j]       = a0 + vA0;  q0[j + 150] = b0 + vB0;
        q1[j + 1]   = a1 + vA1;  q1[j + 151] = b1 + vB1;
        q2[j + 2]   = a2 + vA2;  q2[j + 152] = b2 + vB2;
        __asm__ volatile("" ::: "memory");   // pin group order (cross-lane RAW, dist 3)
    }

    __syncthreads();
    // merge 3 parities x 4 wave windows + masked global flush
    for (int i = tid; i < 555; i += 256) {
        float sum = 0.f;
        #pragma unroll
        for (int w = 0; w < 4; ++w) {
            const int idx = i - (w << 6);
            if (idx >= 0 && idx < 363) {
                const int o = w * 368 + idx;
                sum += w3[0][o] + w3[1][o] + w3[2][o];
            }
        }
        const int pos = s0 + i;
        if (pos < SEQ) {
            (void)__hip_atomic_fetch_add(&kin[(size_t)imu * SEQ + pos], sum,
                                         __ATOMIC_RELAXED, __HIP_MEMORY_SCOPE_AGENT);
        }
    }
}

extern "C" void kernel_launch(void* const* d_in, const int* in_sizes, int n_in,
                              void* d_out, int out_size, void* d_ws, size_t ws_size,
                              hipStream_t stream) {
    const float* hs    = (const float*)d_in[0];
    const float* gamma = (const float*)d_in[1];
    const float* beta  = (const float*)d_in[2];
    const float* W     = (const float*)d_in[3];
    const float* b     = (const float*)d_in[4];
    float* out = (float*)d_out;

    short* A2f = (short*)d_ws;                        // 16.78 MB
    short* Btf = A2f + A2F_SHORTS;                    //  3.67 MB
    float* pt  = (float*)(Btf + BTF_SHORTS);          // 14.16 MB (planes 0..7 used)

    hipMemsetAsync(out, 0, (size_t)PLANE * sizeof(float), stream);

    ln_kernel<<<SEQ / 16, 256, 0, stream>>>(hs, gamma, beta, A2f);
    wprep_kernel<<<dim3(DM / 32, NJ / 32), 256, 0, stream>>>(W, Btf);
    gemm_kernel<<<224, 256, 0, stream>>>(A2f, Btf, b, pt, out);
    spring_kernel<<<dim3(SEQ / 256, NIMU), 256, 0, stream>>>(pt, out);
}

// Round 4
// 149.905 us; speedup vs baseline: 1.0258x; 1.0258x over previous
//
#include <hip/hip_runtime.h>
#include <hip/hip_bf16.h>
#include <math.h>

// Problem constants
#define SEQ 4096
#define DM  1024
#define NIMU 72
#define NNOISE 12
#define NJ (NIMU*NNOISE)     // 864
#define TSTEPS 300
#define PLANE (NIMU*SEQ)     // 294912

// Fragment-linear layouts (16x16x32 bf16 MFMA operand granules):
//   granule(tile, ch) = 512 shorts; lane l holds 8 shorts at +l*8:
//     row = l&15 (m or n), k = ch*32 + (l>>4)*8 + 0..7
//   ch 0..31 = hi half (k 0..1023), ch 32..63 = lo half.
// A2f : 256 s_tiles x 64 ch x 512 shorts = 16.78 MB
// Btf : 56  j_tiles x 64 ch x 512 shorts =  3.67 MB (j_tiles 54,55 unwritten junk)
// pt  : 864 x 4096 f32 (planes >= 576 never written/read after R11 epilogue fold)
#define A2F_SHORTS ((size_t)256 * 64 * 512)
#define BTF_SHORTS ((size_t)56 * 64 * 512)

typedef __attribute__((ext_vector_type(8))) short bf16x8;
typedef __attribute__((ext_vector_type(4))) float f32x4;
typedef __attribute__((ext_vector_type(2))) float f32x2;

__device__ __forceinline__ float softplus_f(float x) {
    return fmaxf(x, 0.f) + log1pf(expf(-fabsf(x)));
}

// round-to-nearest-even bf16 split: x ~= hi + lo with |err| ~ 2^-16 * |x|
__device__ __forceinline__ void split_bf16(float x, short& hi, short& lo) {
    unsigned b = __float_as_uint(x);
    unsigned h = (b + 0x7FFFu + ((b >> 16) & 1u)) >> 16;
    float hf = __uint_as_float(h << 16);
    float r = x - hf;
    unsigned b2 = __float_as_uint(r);
    unsigned l2 = (b2 + 0x7FFFu + ((b2 >> 16) & 1u)) >> 16;
    hi = (short)h;
    lo = (short)l2;
}

// ---------------- 1. LayerNorm -> A2f (fragment-linear bf16 hi|lo) ----------------
__global__ __launch_bounds__(256) void ln_kernel(const float* __restrict__ x,
                                                 const float* __restrict__ gamma,
                                                 const float* __restrict__ beta,
                                                 short* __restrict__ A2f) {
    const int s_tile = blockIdx.x;
    const int tid = threadIdx.x;
    const int mrow = tid >> 4;      // row within s_tile
    const int g    = tid & 15;
    const int row  = s_tile * 16 + mrow;
    const float4* xr = (const float4*)(x + (size_t)row * DM);

    float s = 0.f, sq = 0.f;
    #pragma unroll
    for (int i = 0; i < 16; ++i) {
        float4 v = xr[g + 16 * i];
        s  += v.x + v.y + v.z + v.w;
        sq += v.x*v.x + v.y*v.y + v.z*v.z + v.w*v.w;
    }
    #pragma unroll
    for (int off = 1; off < 16; off <<= 1) {
        s  += __shfl_xor(s, off);
        sq += __shfl_xor(sq, off);
    }
    const float mean = s * (1.f / DM);
    const float var  = sq * (1.f / DM) - mean * mean;
    const float rstd = rsqrtf(fmaxf(var, 0.f) + 1e-5f);

    #pragma unroll
    for (int i = 0; i < 16; ++i) {
        float4 v = xr[g + 16 * i];
        float4 gm = ((const float4*)gamma)[g + 16 * i];
        float4 bt = ((const float4*)beta)[g + 16 * i];
        float o[4];
        o[0] = (v.x - mean) * rstd * gm.x + bt.x;
        o[1] = (v.y - mean) * rstd * gm.y + bt.y;
        o[2] = (v.z - mean) * rstd * gm.z + bt.z;
        o[3] = (v.w - mean) * rstd * gm.w + bt.w;
        short4 hv, lv;
        split_bf16(o[0], hv.x, lv.x);
        split_bf16(o[1], hv.y, lv.y);
        split_bf16(o[2], hv.z, lv.z);
        split_bf16(o[3], hv.w, lv.w);
        const int ch = (g >> 3) + 2 * i;
        const size_t base = ((size_t)s_tile * 64 + ch) * 512
                          + mrow * 8 + ((g >> 1) & 3) * 128 + (g & 1) * 4;
        *(short4*)(A2f + base)             = hv;   // hi: ch
        *(short4*)(A2f + base + 32 * 512)  = lv;   // lo: ch+32
    }
}

// ---------------- 2a. W -> Btf (transpose + split, fragment-linear) ----------------
__global__ __launch_bounds__(256) void wprep_kernel(const float* __restrict__ W,
                                                    short* __restrict__ Btf) {
    __shared__ float T[32][33];
    const int k0 = blockIdx.x * 32, j0 = blockIdx.y * 32;
    const int t = threadIdx.x;
    {
        const int r = t >> 3, c4 = (t & 7) * 4;
        float4 v = *(const float4*)(W + (size_t)(k0 + r) * NJ + j0 + c4);
        T[r][c4 + 0] = v.x; T[r][c4 + 1] = v.y; T[r][c4 + 2] = v.z; T[r][c4 + 3] = v.w;
    }
    __syncthreads();
    if (t < 128) {
        const int gq = t >> 6;          // which 16-j group
        const int l  = t & 63;
        const int n = l & 15, c = l >> 4;
        const int jt = blockIdx.y * 2 + gq;       // j_tile
        bf16x8 hv, lv;
        #pragma unroll
        for (int o = 0; o < 8; ++o) {
            short h, lo_;
            split_bf16(T[c * 8 + o][gq * 16 + n], h, lo_);
            hv[o] = h; lv[o] = lo_;
        }
        short* dh = Btf + ((size_t)jt * 64 + blockIdx.x) * 512 + l * 8;
        *(bf16x8*)dh = hv;
        *(bf16x8*)(dh + (size_t)32 * 512) = lv;   // lo chunk = ch+32
    }
}

// ---------------- 2b. Barrier-free MFMA GEMM + fused tail epilogue ----------------
// R11 counters: dur 47.5us, Occupancy 5.7%, MfmaUtil 17%, HBM 10% -> latency-bound
// at 1 wave/SIMD (224 blocks x 4 waves on 256 CUs; every vmcnt wait fully exposed).
// R12: 512-thread blocks (8 waves), same 224-block grid, same 128x128 tile ->
// 2 waves/SIMD; wave tile 4x2 (12 loads, 24 MFMA per k-step, ratio 2:1). The other
// wave's MFMA block covers this wave's L2/HBM latency. Still barrier-free.
// XCD swizzle (R11a) + fused tail (R11b) unchanged.
__global__ __launch_bounds__(512, 2) void gemm_kernel(const short* __restrict__ A2f,
                                                      const short* __restrict__ Btf,
                                                      const float* __restrict__ bias,
                                                      float* __restrict__ pt,
                                                      float* __restrict__ out) {
    const int bid = blockIdx.x;
    const int c = bid & 7, k = bid >> 3;
    const int kd7 = k / 7;
    const int bx = c * 4 + kd7;
    const int by = k - kd7 * 7;
    const int l = threadIdx.x & 63, w = threadIdx.x >> 6;   // w in 0..7
    const int st0 = bx * 8 + (w & 1) * 4;    // wave's m-tile base (4 tiles)
    const int jt0 = by * 8 + (w >> 1) * 2;   // wave's n-tile base (2 tiles)
    const short* aB = A2f + (size_t)st0 * (64 * 512) + l * 8;
    const short* bB = Btf + (size_t)jt0 * (64 * 512) + l * 8;

    f32x4 acc[4][2] = {};
    bf16x8 ah[2][4], al[2][4], bh[2][2], bl[2][2];

    auto ldstep = [&](int slot, int i) {
        #pragma unroll
        for (int t = 0; t < 4; ++t) {
            ah[slot][t] = *(const bf16x8*)(aB + ((size_t)t * 64 + i) * 512);
            al[slot][t] = *(const bf16x8*)(aB + ((size_t)t * 64 + 32 + i) * 512);
        }
        #pragma unroll
        for (int t = 0; t < 2; ++t) {
            bh[slot][t] = *(const bf16x8*)(bB + ((size_t)t * 64 + i) * 512);
            bl[slot][t] = *(const bf16x8*)(bB + ((size_t)t * 64 + 32 + i) * 512);
        }
    };

    ldstep(0, 0);
    #pragma unroll 2
    for (int i = 0; i < 32; ++i) {
        const int cur = i & 1;
        if (i + 1 < 32) ldstep(cur ^ 1, i + 1);   // loads in flight during MFMA
        #pragma unroll
        for (int mi = 0; mi < 4; ++mi)
            #pragma unroll
            for (int ni = 0; ni < 2; ++ni)
                acc[mi][ni] = __builtin_amdgcn_mfma_f32_16x16x32_bf16(
                    ah[cur][mi], bh[cur][ni], acc[mi][ni], 0, 0, 0);
        #pragma unroll
        for (int mi = 0; mi < 4; ++mi)
            #pragma unroll
            for (int ni = 0; ni < 2; ++ni)
                acc[mi][ni] = __builtin_amdgcn_mfma_f32_16x16x32_bf16(
                    ah[cur][mi], bl[cur][ni], acc[mi][ni], 0, 0, 0);
        #pragma unroll
        for (int mi = 0; mi < 4; ++mi)
            #pragma unroll
            for (int ni = 0; ni < 2; ++ni)
                acc[mi][ni] = __builtin_amdgcn_mfma_f32_16x16x32_bf16(
                    al[cur][mi], bh[cur][ni], acc[mi][ni], 0, 0, 0);
    }

    // epilogue: C/D layout col=lane&15 (j-within-tile), row=(lane>>4)*4+reg (s)
    const int srow = (l >> 4) * 4;
    const int jcol = l & 15;
    #pragma unroll
    for (int ni = 0; ni < 2; ++ni) {
        const int jt = jt0 + ni;
        const int j = jt * 16 + jcol;
        if (j < NJ) {
            const float bj = bias[j];
            if (jt < 36) {                       // noise planes 0..7 -> pt (spring input)
                #pragma unroll
                for (int mi = 0; mi < 4; ++mi) {
                    f32x4 v = acc[mi][ni];
                    v[0] += bj; v[1] += bj; v[2] += bj; v[3] += bj;
                    *(f32x4*)(pt + (size_t)j * SEQ + (st0 + mi) * 16 + srow) = v;
                }
            } else {                             // noise planes 8..11 -> out directly
                const int noise = j / 72;        // 8..11
                const int imu = j - noise * 72;
                float* dst = out + (size_t)(noise - 7) * PLANE + (size_t)imu * SEQ;
                const bool sp = (noise & 1);
                #pragma unroll
                for (int mi = 0; mi < 4; ++mi) {
                    f32x4 v = acc[mi][ni];
                    v[0] += bj; v[1] += bj; v[2] += bj; v[3] += bj;
                    if (sp) {
                        v[0] = softplus_f(v[0]); v[1] = softplus_f(v[1]);
                        v[2] = softplus_f(v[2]); v[3] = softplus_f(v[3]);
                    }
                    *(f32x4*)(dst + (st0 + mi) * 16 + srow) = v;
                }
            }
        }
    }
}

// ---------------- 3. Spring recurrence + wave-private LDS-window scatter ----------------
// R10 (146us total): wave-private window, RMW chain ds_read2 -> wait -> add ->
// ds_write2 -> barrier = ONE full LDS-latency stall per macro-step (150 waits).
// R11: 3-parity buffers w3[j%3]. A barrier-group = 3 macro-steps; each buffer is
// RMW'd at exactly one step index per group (plus the B-stream +150 slot: lane
// distance 150 > 63 -> race-free), so all 6 reads issue together -> ONE lgkm wait
// per 3 macro-steps (50 waits). Cross-group RAW (lane l reads what lane l+3 wrote
// last group) pinned by one memory-clobber per group + in-order LDS pipe.
__global__ __launch_bounds__(256) void spring_kernel(const float* __restrict__ pt,
                                                     float* __restrict__ kin) {
    __shared__ float w3[3][4 * 368];           // 363 used per wave per parity
    const int tid  = threadIdx.x;
    const int lane = tid & 63;
    const int wid  = tid >> 6;
    const int s0   = blockIdx.x * 256;
    const int imu  = blockIdx.y;
    const int s    = s0 + (wid << 6) + lane;

    // zero own windows (wave-private: no barrier needed before main loop)
    #pragma unroll
    for (int b = 0; b < 3; ++b)
        #pragma unroll
        for (int i = 0; i < 6; ++i) {
            const int idx = lane + i * 64;
            if (idx < 363) w3[b][wid * 368 + idx] = 0.f;
        }

    const int base = imu * SEQ + s;
    const float p0  = pt[(size_t)0 * PLANE + base];
    const float p1  = pt[(size_t)1 * PLANE + base];
    const float p2  = pt[(size_t)2 * PLANE + base];
    const float p3  = pt[(size_t)3 * PLANE + base];
    const float c1  = pt[(size_t)4 * PLANE + base];
    const float c2  = pt[(size_t)5 * PLANE + base];
    const float ph1 = pt[(size_t)6 * PLANE + base];
    const float ph2 = pt[(size_t)7 * PLANE + base];

    float dd = softplus_f(p1);
    float kk = dd * dd * 0.25f + softplus_f(p0);
    float om1 = 0.5f * sqrtf(fmaxf(4.f * kk - dd * dd, 0.f));
    float dt = softplus_f(p3);
    float kt = dt * dt * 0.25f + softplus_f(p2);
    float om2 = 0.5f * sqrtf(fmaxf(4.f * kt - dt * dt, 0.f));
    float e1 = expf(-0.5f * dd), e2 = expf(-0.5f * dt);
    float sn, cs, sn2, cs2;
    sincosf(om1, &sn, &cs);
    sincosf(om2, &sn2, &cs2);
    f32x2 Rr = {e1 * cs, e2 * cs2};          // per-step rotation (packed: osc1, osc2)
    f32x2 Ri = {e1 * sn, e2 * sn2};
    sincosf(ph1, &sn, &cs);
    sincosf(ph2, &sn2, &cs2);
    f32x2 zr = {c1 * cs, c2 * cs2};          // stream A state (t = 0)
    f32x2 zi = {c1 * sn, c2 * sn2};

    // stream B state: z * R^150 (exp-by-squaring)
    f32x2 zrB, ziB;
    {
        f32x2 prr = Rr, pri = Ri;
        f32x2 qr = {1.f, 1.f}, qi = {0.f, 0.f};
        int e = 150;
        while (e) {
            if (e & 1) {
                f32x2 nr = qr * prr - qi * pri;
                qi = qr * pri + qi * prr;
                qr = nr;
            }
            f32x2 nr = prr * prr - pri * pri;
            pri = 2.f * prr * pri;
            prr = nr;
            e >>= 1;
        }
        f32x2 nr = zr * qr - zi * qi;
        ziB = zr * qi + zi * qr;
        zrB = nr;
    }

    float* q0 = &w3[0][wid * 368 + lane];
    float* q1 = &w3[1][wid * 368 + lane];
    float* q2 = &w3[2][wid * 368 + lane];

    #pragma unroll 1
    for (int j = 0; j < 150; j += 3) {
        // values for macro-steps j, j+1, j+2 on both streams
        float vA0 = zi.x + zi.y;
        { f32x2 nr = zr * Rr - zi * Ri; zi = zr * Ri + zi * Rr; zr = nr; }
        float vA1 = zi.x + zi.y;
        { f32x2 nr = zr * Rr - zi * Ri; zi = zr * Ri + zi * Rr; zr = nr; }
        float vA2 = zi.x + zi.y;
        { f32x2 nr = zr * Rr - zi * Ri; zi = zr * Ri + zi * Rr; zr = nr; }
        float vB0 = ziB.x + ziB.y;
        { f32x2 nr = zrB * Rr - ziB * Ri; ziB = zrB * Ri + ziB * Rr; zrB = nr; }
        float vB1 = ziB.x + ziB.y;
        { f32x2 nr = zrB * Rr - ziB * Ri; ziB = zrB * Ri + ziB * Rr; zrB = nr; }
        float vB2 = ziB.x + ziB.y;
        { f32x2 nr = zrB * Rr - ziB * Ri; ziB = zrB * Ri + ziB * Rr; zrB = nr; }

        // all 6 reads issue together -> single lgkm wait per group
        const float a0 = q0[j],     b0 = q0[j + 150];
        const float a1 = q1[j + 1], b1 = q1[j + 151];
        const float a2 = q2[j + 2], b2 = q2[j + 152];
        q0[j]       = a0 + vA0;  q0[j + 150] = b0 + vB0;
        q1[j + 1]   = a1 + vA1;  q1[j + 151] = b1 + vB1;
        q2[j + 2]   = a2 + vA2;  q2[j + 152] = b2 + vB2;
        __asm__ volatile("" ::: "memory");   // pin group order (cross-lane RAW, dist 3)
    }

    __syncthreads();
    // merge 3 parities x 4 wave windows + masked global flush
    for (int i = tid; i < 555; i += 256) {
        float sum = 0.f;
        #pragma unroll
        for (int w = 0; w < 4; ++w) {
            const int idx = i - (w << 6);
            if (idx >= 0 && idx < 363) {
                const int o = w * 368 + idx;
                sum += w3[0][o] + w3[1][o] + w3[2][o];
            }
        }
        const int pos = s0 + i;
        if (pos < SEQ) {
            (void)__hip_atomic_fetch_add(&kin[(size_t)imu * SEQ + pos], sum,
                                         __ATOMIC_RELAXED, __HIP_MEMORY_SCOPE_AGENT);
        }
    }
}

extern "C" void kernel_launch(void* const* d_in, const int* in_sizes, int n_in,
                              void* d_out, int out_size, void* d_ws, size_t ws_size,
                              hipStream_t stream) {
    const float* hs    = (const float*)d_in[0];
    const float* gamma = (const float*)d_in[1];
    const float* beta  = (const float*)d_in[2];
    const float* W     = (const float*)d_in[3];
    const float* b     = (const float*)d_in[4];
    float* out = (float*)d_out;

    short* A2f = (short*)d_ws;                        // 16.78 MB
    short* Btf = A2f + A2F_SHORTS;                    //  3.67 MB
    float* pt  = (float*)(Btf + BTF_SHORTS);          // 14.16 MB (planes 0..7 used)

    hipMemsetAsync(out, 0, (size_t)PLANE * sizeof(float), stream);

    ln_kernel<<<SEQ / 16, 256, 0, stream>>>(hs, gamma, beta, A2f);
    wprep_kernel<<<dim3(DM / 32, NJ / 32), 256, 0, stream>>>(W, Btf);
    gemm_kernel<<<224, 512, 0, stream>>>(A2f, Btf, b, pt, out);
    spring_kernel<<<dim3(SEQ / 256, NIMU), 256, 0, stream>>>(pt, out);
}